// Round 8
// baseline (47.601 us; speedup 1.0000x reference)
//
#include <hip/hip_runtime.h>

#define BATCH 8
#define NTOK 4096
#define CH 256
#define IMG 1024
#define PATCH 16
#define CHUNKS 32                    // blocks per (batch, input)
#define TPB (NTOK / CHUNKS)          // 128 tokens per block
#define PART_STRIDE 520              // per-block partial: 256 W + 256 S + scalars
#define NBLK_STATS (2 * BATCH * CHUNKS)  // 512

// ws layout: block bid (= is_q*256 + b*32 + chunk) owns floats
//   [bid*520 + 0,   256)  W[c] = sum_n m * e      (pos_num or u)
//   [bid*520 + 256, 512)  S[c] = sum_n e          (sum_e or v)
//   [bid*520 + 512]       sum_n m
//   [bid*520 + 513]       sum_n m*||e||^2  (q only, else 0)
//   [bid*520 + 514]       sum_n ||e||^2    (q only, else 0)
//
// R8 is a MEASUREMENT ROUND: stats_kernel is launched 3x (writes are
// idempotent), so dur_us = base(22.86) + 2*stats_dur. This pins the
// stats/finalize/overhead budget split before the next optimization.

__device__ __forceinline__ float wave_reduce_sum(float v) {
    for (int off = 32; off > 0; off >>= 1) v += __shfl_down(v, off, 64);
    return v;
}

__global__ __launch_bounds__(256) void stats_kernel(
    const float* __restrict__ ep_e, const float* __restrict__ ep_m,
    const float* __restrict__ q_e,  const float* __restrict__ q_m,
    float* __restrict__ ws, float* __restrict__ out)
{
    const int bid = blockIdx.x;
    const int tid = threadIdx.x;
    if (bid == 0 && tid < 3) out[tid] = 0.f;   // finalize accumulates into out

    const bool is_q = (bid >= BATCH * CHUNKS);
    const int lb    = bid & (BATCH * CHUNKS - 1);
    const int b     = lb >> 5;                  // /CHUNKS
    const int start = (lb & (CHUNKS - 1)) * TPB;

    const float* __restrict__ embed = is_q ? q_e : ep_e;
    const float* __restrict__ mask  = is_q ? q_m : ep_m;

    const int w = tid >> 6, lane = tid & 63, cbase = lane << 2;

    float4 accW = {0.f, 0.f, 0.f, 0.f};
    float4 accS = {0.f, 0.f, 0.f, 0.f};
    float accA = 0.f, accB = 0.f, accm = 0.f;

    const float* ebase = embed + (size_t)(b * NTOK + start) * CH + cbase;
    const size_t mbase = (size_t)b * IMG * IMG;

    const int t0 = w * 32;   // this wave's 32 contiguous tokens
    #pragma unroll
    for (int bat = 0; bat < 4; ++bat) {
        float4 e[8];
        float  mm[8];
        #pragma unroll
        for (int k = 0; k < 8; ++k) {
            const int t = t0 + bat * 8 + k;
            const int n = start + t;
            mm[k] = mask[mbase + (size_t)((n >> 6) * PATCH) * IMG + (size_t)((n & 63) * PATCH)];
            e[k]  = *reinterpret_cast<const float4*>(ebase + (size_t)t * CH);
        }
        #pragma unroll
        for (int k = 0; k < 8; ++k) {
            const float m = mm[k];
            accW.x += m * e[k].x; accW.y += m * e[k].y;
            accW.z += m * e[k].z; accW.w += m * e[k].w;
            accS.x += e[k].x;     accS.y += e[k].y;
            accS.z += e[k].z;     accS.w += e[k].w;
            if (is_q) {
                const float d = e[k].x * e[k].x + e[k].y * e[k].y
                              + e[k].z * e[k].z + e[k].w * e[k].w;
                accA += m * d;
                accB += d;
            }
            accm += m;   // wave-uniform
        }
    }

    // cross-wave reduce (all 4 waves cover the same 256 channels)
    __shared__ __align__(16) float ldsW[4][CH];
    __shared__ __align__(16) float ldsS[4][CH];
    __shared__ float ldsA[4], ldsB[4], ldsM[4];

    *reinterpret_cast<float4*>(&ldsW[w][cbase]) = accW;
    *reinterpret_cast<float4*>(&ldsS[w][cbase]) = accS;
    if (is_q) {
        accA = wave_reduce_sum(accA);
        accB = wave_reduce_sum(accB);
    }
    if (lane == 0) { ldsA[w] = accA; ldsB[w] = accB; ldsM[w] = accm; }
    __syncthreads();

    float* p = ws + (size_t)bid * PART_STRIDE;
    const int c = tid;
    p[c]      = ldsW[0][c] + ldsW[1][c] + ldsW[2][c] + ldsW[3][c];
    p[CH + c] = ldsS[0][c] + ldsS[1][c] + ldsS[2][c] + ldsS[3][c];
    if (tid == 0) {
        p[512] = ldsM[0] + ldsM[1] + ldsM[2] + ldsM[3];
        p[513] = is_q ? (ldsA[0] + ldsA[1] + ldsA[2] + ldsA[3]) : 0.f;
        p[514] = is_q ? (ldsB[0] + ldsB[1] + ldsB[2] + ldsB[3]) : 0.f;
    }
}

__global__ __launch_bounds__(256) void finalize_kernel(
    const float* __restrict__ ws, float* __restrict__ out)
{
    const int b   = blockIdx.x;     // one block per batch element
    const int tid = threadIdx.x;    // one thread per channel

    float pn = 0.f, se = 0.f, uu = 0.f, vv = 0.f;
    #pragma unroll 8
    for (int k = 0; k < CHUNKS; ++k) {
        const float* pe = ws + (size_t)(b * CHUNKS + k) * PART_STRIDE;
        const float* pq = pe + (size_t)(BATCH * CHUNKS) * PART_STRIDE;
        pn += pe[tid];      se += pe[CH + tid];
        uu += pq[tid];      vv += pq[CH + tid];
    }

    // batch scalars: chunk k handled by lane k of wave 0
    __shared__ float sc[4];   // cnt_ep, A, Bq, npos
    if (tid < 64) {
        float c0 = 0.f, a0 = 0.f, b0 = 0.f, n0 = 0.f;
        if (tid < CHUNKS) {
            const float* pe = ws + (size_t)(b * CHUNKS + tid) * PART_STRIDE;
            const float* pq = pe + (size_t)(BATCH * CHUNKS) * PART_STRIDE;
            c0 = pe[512]; a0 = pq[513]; b0 = pq[514]; n0 = pq[512];
        }
        c0 = wave_reduce_sum(c0); a0 = wave_reduce_sum(a0);
        b0 = wave_reduce_sum(b0); n0 = wave_reduce_sum(n0);
        if (tid == 0) { sc[0] = c0; sc[1] = a0; sc[2] = b0; sc[3] = n0; }
    }
    __syncthreads();

    const float cnt = sc[0], A = sc[1], Bv = sc[2], np = sc[3];
    const float pc = pn / (cnt + 0.1f);
    const float nc = (se - pn) / (((float)NTOK - cnt) + 0.1f);

    float4 t;
    t.x = uu * pc;          // u . p
    t.y = (vv - uu) * nc;   // (v-u) . n
    t.z = pc * pc;          // ||p||^2
    t.w = nc * nc;          // ||n||^2

    __shared__ float4 red[256];
    red[tid] = t;
    __syncthreads();
    for (int s = 128; s > 0; s >>= 1) {
        if (tid < s) {
            red[tid].x += red[tid + s].x;
            red[tid].y += red[tid + s].y;
            red[tid].z += red[tid + s].z;
            red[tid].w += red[tid + s].w;
        }
        __syncthreads();
    }

    if (tid == 0) {
        const float nn = (float)NTOK - np;
        const float pos_term = A - 2.f * red[0].x + np * red[0].z;
        const float neg_term = (Bv - A) - 2.f * red[0].y + nn * red[0].w;
        const float pos_loss = (np > 0.f) ? pos_term / (fmaxf(np, 1.f) * (float)CH) : 0.f;
        const float neg_loss = (nn > 0.f) ? neg_term / (fmaxf(nn, 1.f) * (float)CH) : 0.f;
        const float inv_b = 1.f / (float)BATCH;
        atomicAdd(&out[0], (pos_loss + neg_loss) * inv_b);
        atomicAdd(&out[1], pos_loss * inv_b);
        atomicAdd(&out[2], neg_loss * inv_b);
    }
}

extern "C" void kernel_launch(void* const* d_in, const int* in_sizes, int n_in,
                              void* d_out, int out_size, void* d_ws, size_t ws_size,
                              hipStream_t stream) {
    const float* ep_e = (const float*)d_in[0];  // ep_mask_embed (8,4096,256)
    const float* ep_m = (const float*)d_in[1];  // ep_mask (8,1,1024,1024)
    const float* q_e  = (const float*)d_in[2];  // query_mask_embed
    const float* q_m  = (const float*)d_in[3];  // query_mask
    float* out = (float*)d_out;
    float* ws  = (float*)d_ws;

    // MEASUREMENT: 3x stats (idempotent overwrites) => dur = base + 2*stats
    stats_kernel<<<NBLK_STATS, 256, 0, stream>>>(ep_e, ep_m, q_e, q_m, ws, out);
    stats_kernel<<<NBLK_STATS, 256, 0, stream>>>(ep_e, ep_m, q_e, q_m, ws, out);
    stats_kernel<<<NBLK_STATS, 256, 0, stream>>>(ep_e, ep_m, q_e, q_m, ws, out);
    finalize_kernel<<<BATCH, 256, 0, stream>>>(ws, out);
}

// Round 9
// 21.339 us; speedup vs baseline: 2.2307x; 2.2307x over previous
//
#include <hip/hip_runtime.h>

#define BATCH 8
#define NTOK 4096
#define CH 256
#define IMG 1024
#define PATCH 16
#define CHUNKS 32                    // blocks per (batch, input)
#define TPB (NTOK / CHUNKS)          // 128 tokens per block
#define PART_STRIDE 520              // per-block partial: 256 W + 256 S + scalars
#define NBLK_STATS (2 * BATCH * CHUNKS)  // 512

// ws layout: block bid (= is_q*256 + b*32 + chunk) owns floats
//   [bid*520 + 0,   256)  W[c] = sum_n m * e      (pos_num or u)
//   [bid*520 + 256, 512)  S[c] = sum_n e          (sum_e or v)
//   [bid*520 + 512]       sum_n m
//   [bid*520 + 513]       sum_n m*||e||^2  (q only, else 0)
//   [bid*520 + 514]       sum_n ||e||^2    (q only, else 0)
//
// R8 measured: stats = 12.4 us (~BW ceiling), finalize+overhead = 10.5 us.
// R9: finalize rewritten for MLP — 512 thr, float4 loads, 8 kk-groups.

__device__ __forceinline__ float wave_reduce_sum(float v) {
    for (int off = 32; off > 0; off >>= 1) v += __shfl_down(v, off, 64);
    return v;
}

__global__ __launch_bounds__(256) void stats_kernel(
    const float* __restrict__ ep_e, const float* __restrict__ ep_m,
    const float* __restrict__ q_e,  const float* __restrict__ q_m,
    float* __restrict__ ws, float* __restrict__ out)
{
    const int bid = blockIdx.x;
    const int tid = threadIdx.x;
    if (bid == 0 && tid < 3) out[tid] = 0.f;   // finalize accumulates into out

    const bool is_q = (bid >= BATCH * CHUNKS);
    const int lb    = bid & (BATCH * CHUNKS - 1);
    const int b     = lb >> 5;                  // /CHUNKS
    const int start = (lb & (CHUNKS - 1)) * TPB;

    const float* __restrict__ embed = is_q ? q_e : ep_e;
    const float* __restrict__ mask  = is_q ? q_m : ep_m;

    const int w = tid >> 6, lane = tid & 63, cbase = lane << 2;

    float4 accW = {0.f, 0.f, 0.f, 0.f};
    float4 accS = {0.f, 0.f, 0.f, 0.f};
    float accA = 0.f, accB = 0.f, accm = 0.f;

    const float* ebase = embed + (size_t)(b * NTOK + start) * CH + cbase;
    const size_t mbase = (size_t)b * IMG * IMG;

    const int t0 = w * 32;   // this wave's 32 contiguous tokens
    #pragma unroll
    for (int bat = 0; bat < 4; ++bat) {
        float4 e[8];
        float  mm[8];
        #pragma unroll
        for (int k = 0; k < 8; ++k) {
            const int t = t0 + bat * 8 + k;
            const int n = start + t;
            mm[k] = mask[mbase + (size_t)((n >> 6) * PATCH) * IMG + (size_t)((n & 63) * PATCH)];
            e[k]  = *reinterpret_cast<const float4*>(ebase + (size_t)t * CH);
        }
        #pragma unroll
        for (int k = 0; k < 8; ++k) {
            const float m = mm[k];
            accW.x += m * e[k].x; accW.y += m * e[k].y;
            accW.z += m * e[k].z; accW.w += m * e[k].w;
            accS.x += e[k].x;     accS.y += e[k].y;
            accS.z += e[k].z;     accS.w += e[k].w;
            if (is_q) {
                const float d = e[k].x * e[k].x + e[k].y * e[k].y
                              + e[k].z * e[k].z + e[k].w * e[k].w;
                accA += m * d;
                accB += d;
            }
            accm += m;   // wave-uniform
        }
    }

    // cross-wave reduce (all 4 waves cover the same 256 channels)
    __shared__ __align__(16) float ldsW[4][CH];
    __shared__ __align__(16) float ldsS[4][CH];
    __shared__ float ldsA[4], ldsB[4], ldsM[4];

    *reinterpret_cast<float4*>(&ldsW[w][cbase]) = accW;
    *reinterpret_cast<float4*>(&ldsS[w][cbase]) = accS;
    if (is_q) {
        accA = wave_reduce_sum(accA);
        accB = wave_reduce_sum(accB);
    }
    if (lane == 0) { ldsA[w] = accA; ldsB[w] = accB; ldsM[w] = accm; }
    __syncthreads();

    float* p = ws + (size_t)bid * PART_STRIDE;
    const int c = tid;
    p[c]      = ldsW[0][c] + ldsW[1][c] + ldsW[2][c] + ldsW[3][c];
    p[CH + c] = ldsS[0][c] + ldsS[1][c] + ldsS[2][c] + ldsS[3][c];
    if (tid == 0) {
        p[512] = ldsM[0] + ldsM[1] + ldsM[2] + ldsM[3];
        p[513] = is_q ? (ldsA[0] + ldsA[1] + ldsA[2] + ldsA[3]) : 0.f;
        p[514] = is_q ? (ldsB[0] + ldsB[1] + ldsB[2] + ldsB[3]) : 0.f;
    }
}

// 8 blocks (one per batch) x 512 threads. kk = tid>>6 picks a chunk subgroup;
// each thread streams float4s => ~128 KB in flight per block (vs 16 KB before).
__global__ __launch_bounds__(512) void finalize_kernel(
    const float* __restrict__ ws, float* __restrict__ out)
{
    const int b   = blockIdx.x;
    const int tid = threadIdx.x;
    const int kk  = tid >> 6;     // 0..7 chunk subgroup
    const int l   = tid & 63;     // lane; channels 4l..4l+3
    const int ch4 = l << 2;

    float4 aW = {0,0,0,0}, aS = {0,0,0,0}, aU = {0,0,0,0}, aV = {0,0,0,0};
    #pragma unroll
    for (int p = 0; p < 4; ++p) {
        const int k = p * 8 + kk;
        const float* pe = ws + (size_t)(b * CHUNKS + k) * PART_STRIDE;
        const float* pq = pe + (size_t)(BATCH * CHUNKS) * PART_STRIDE;
        const float4 w4 = *reinterpret_cast<const float4*>(pe + ch4);
        const float4 s4 = *reinterpret_cast<const float4*>(pe + CH + ch4);
        const float4 u4 = *reinterpret_cast<const float4*>(pq + ch4);
        const float4 v4 = *reinterpret_cast<const float4*>(pq + CH + ch4);
        aW.x += w4.x; aW.y += w4.y; aW.z += w4.z; aW.w += w4.w;
        aS.x += s4.x; aS.y += s4.y; aS.z += s4.z; aS.w += s4.w;
        aU.x += u4.x; aU.y += u4.y; aU.z += u4.z; aU.w += u4.w;
        aV.x += v4.x; aV.y += v4.y; aV.z += v4.z; aV.w += v4.w;
    }

    __shared__ __align__(16) float4 LW[8][64], LS[8][64], LU[8][64], LV[8][64];
    __shared__ float sc[4];   // cnt_ep, A, Bq, npos
    LW[kk][l] = aW; LS[kk][l] = aS; LU[kk][l] = aU; LV[kk][l] = aV;
    __syncthreads();

    float4 pn, se, uu, vv;
    if (kk == 0) {
        // wave 0: reduce the 8 subgroups per channel
        pn = LW[0][l]; se = LS[0][l]; uu = LU[0][l]; vv = LV[0][l];
        #pragma unroll
        for (int g = 1; g < 8; ++g) {
            const float4 w4 = LW[g][l], s4 = LS[g][l], u4 = LU[g][l], v4 = LV[g][l];
            pn.x += w4.x; pn.y += w4.y; pn.z += w4.z; pn.w += w4.w;
            se.x += s4.x; se.y += s4.y; se.z += s4.z; se.w += s4.w;
            uu.x += u4.x; uu.y += u4.y; uu.z += u4.z; uu.w += u4.w;
            vv.x += v4.x; vv.y += v4.y; vv.z += v4.z; vv.w += v4.w;
        }
    } else if (kk == 1) {
        // wave 1: batch scalars (chunk l for l < 32)
        float c0 = 0.f, a0 = 0.f, b0 = 0.f, n0 = 0.f;
        if (l < CHUNKS) {
            const float* pe = ws + (size_t)(b * CHUNKS + l) * PART_STRIDE;
            const float* pq = pe + (size_t)(BATCH * CHUNKS) * PART_STRIDE;
            c0 = pe[512]; a0 = pq[513]; b0 = pq[514]; n0 = pq[512];
        }
        c0 = wave_reduce_sum(c0); a0 = wave_reduce_sum(a0);
        b0 = wave_reduce_sum(b0); n0 = wave_reduce_sum(n0);
        if (l == 0) { sc[0] = c0; sc[1] = a0; sc[2] = b0; sc[3] = n0; }
    }
    __syncthreads();

    if (kk == 0) {
        const float cnt = sc[0], A = sc[1], Bv = sc[2], np = sc[3];
        const float id_p = 1.f / (cnt + 0.1f);
        const float id_n = 1.f / (((float)NTOK - cnt) + 0.1f);

        float tx = 0.f, ty = 0.f, tz = 0.f, tw = 0.f;
        #pragma unroll
        for (int i = 0; i < 4; ++i) {
            const float pni = (&pn.x)[i], sei = (&se.x)[i];
            const float uui = (&uu.x)[i], vvi = (&vv.x)[i];
            const float pc = pni * id_p;
            const float nc = (sei - pni) * id_n;
            tx += uui * pc;
            ty += (vvi - uui) * nc;
            tz += pc * pc;
            tw += nc * nc;
        }
        tx = wave_reduce_sum(tx); ty = wave_reduce_sum(ty);
        tz = wave_reduce_sum(tz); tw = wave_reduce_sum(tw);

        if (l == 0) {
            const float nn = (float)NTOK - np;
            const float pos_term = A - 2.f * tx + np * tz;
            const float neg_term = (Bv - A) - 2.f * ty + nn * tw;
            const float pos_loss = (np > 0.f) ? pos_term / (fmaxf(np, 1.f) * (float)CH) : 0.f;
            const float neg_loss = (nn > 0.f) ? neg_term / (fmaxf(nn, 1.f) * (float)CH) : 0.f;
            const float inv_b = 1.f / (float)BATCH;
            atomicAdd(&out[0], (pos_loss + neg_loss) * inv_b);
            atomicAdd(&out[1], pos_loss * inv_b);
            atomicAdd(&out[2], neg_loss * inv_b);
        }
    }
}

extern "C" void kernel_launch(void* const* d_in, const int* in_sizes, int n_in,
                              void* d_out, int out_size, void* d_ws, size_t ws_size,
                              hipStream_t stream) {
    const float* ep_e = (const float*)d_in[0];  // ep_mask_embed (8,4096,256)
    const float* ep_m = (const float*)d_in[1];  // ep_mask (8,1,1024,1024)
    const float* q_e  = (const float*)d_in[2];  // query_mask_embed
    const float* q_m  = (const float*)d_in[3];  // query_mask
    float* out = (float*)d_out;
    float* ws  = (float*)d_ws;

    stats_kernel<<<NBLK_STATS, 256, 0, stream>>>(ep_e, ep_m, q_e, q_m, ws, out);
    finalize_kernel<<<BATCH, 512, 0, stream>>>(ws, out);
}